// Round 5
// baseline (497.258 us; speedup 1.0000x reference)
//
#include <hip/hip_runtime.h>

// Problem: x [B=8, T=16, C=64, H=64, W=64] fp32.
// out = x masked by per-batch top-K (K=2048 of N=4096) spatial sites,
// score[b,n] = mean_t sqrt(sum_c x[b,t,c,n]^2).
//
// Scores computed BIT-IDENTICALLY to numpy (sequential ascending-index
// accumulation, unfused mul/add, IEEE sqrt, *0.0625) -> kept set matches the
// reference exactly -> absmax 0 (verified R1-R7).
//
// R8: single resident kernel. R4/R6/R7 showed cache-policy changes are
// neutral; remaining addressable cost = 2 inter-kernel drain boundaries +
// the 8-CU select window serializing the whole GPU. Fuse:
//   512 blocks x 256 thr (2 blocks/CU -> co-residency guaranteed, spin
//   barriers deadlock-free). Phase1 = k_sq body. Barrier A (atomic counter,
//   zeroed via hipMemsetAsync pre-launch). Phase2 = select on blocks 0..7,
//   per-batch release flag = MAGIC. Phase3 = apply; block g waits only on
//   flag[g>>6] -> apply(b) overlaps select(b+1..7).
// All math bodies byte-identical to verified R6 kernels.

constexpr int NB = 8;
constexpr int NT = 16;
constexpr int NC = 64;
constexpr int NN = 4096;   // H*W
constexpr int KK = 2048;   // keep_k

constexpr unsigned MAGIC = 0x1F2E3D4Cu;   // not a repeated-byte poison pattern

typedef float vf4 __attribute__((ext_vector_type(4)));  // raw vec for nt builtins

// ---------------- Shared selection body (verified bisection w/ prefix skip) ---
// u[16] = score bits for sites n = tid*16 .. tid*16+15 (nonneg floats ->
// bit pattern is order-preserving). Emits mask[b*NN + ...].
__device__ __forceinline__ void topk_emit_mask(const unsigned* u, int b, int tid,
                                               float* __restrict__ mask) {
    __shared__ unsigned s_red[2][4];
    __shared__ unsigned s_scan[4];
    int wave = tid >> 6, lane = tid & 63;

    // --- block min/max of u -> common high-bit prefix ---
    unsigned lmin = u[0], lmax = u[0];
    #pragma unroll
    for (int k = 1; k < 16; ++k) {
        lmin = min(lmin, u[k]);
        lmax = max(lmax, u[k]);
    }
    #pragma unroll
    for (int off = 32; off > 0; off >>= 1) {
        lmin = min(lmin, (unsigned)__shfl_down((int)lmin, off, 64));
        lmax = max(lmax, (unsigned)__shfl_down((int)lmax, off, 64));
    }
    if (lane == 0) { s_red[0][wave] = lmin; s_red[1][wave] = lmax; }
    __syncthreads();
    unsigned umin = s_red[0][0], umax = s_red[1][0];
    #pragma unroll
    for (int w = 1; w < 4; ++w) {
        umin = min(umin, s_red[0][w]);
        umax = max(umax, s_red[1][w]);
    }
    __syncthreads();

    // --- bisection: max T with count(u >= T) >= KK (T = K-th largest bits) ---
    unsigned T;
    if (umax == umin) {
        T = umax;                      // all equal: pure tie case
    } else {
        int hb = 31 - __clz(umax ^ umin);      // hb <= 30 (scores >= 0)
        T = umax & ~((2u << hb) - 1);          // shared prefix, low bits 0
        for (int bit = hb; bit >= 0; --bit) {
            unsigned C = T | (1u << bit);
            int local = 0;
            #pragma unroll
            for (int k = 0; k < 16; ++k) local += (int)(u[k] >= C);
            #pragma unroll
            for (int off = 32; off > 0; off >>= 1)
                local += __shfl_down(local, off, 64);
            if (lane == 0) s_red[bit & 1][wave] = (unsigned)local;
            __syncthreads();
            int total = (int)s_red[bit & 1][0] + (int)s_red[bit & 1][1] +
                        (int)s_red[bit & 1][2] + (int)s_red[bit & 1][3];
            if (total >= KK) T = C;
            // alternating slot: entry reused two iters later, separated by a sync
        }
    }

    // --- cnt_gt = count(u > T) ---
    {
        int local = 0;
        #pragma unroll
        for (int k = 0; k < 16; ++k) local += (int)(u[k] > T);
        #pragma unroll
        for (int off = 32; off > 0; off >>= 1)
            local += __shfl_down(local, off, 64);
        __syncthreads();
        if (lane == 0) s_red[0][wave] = (unsigned)local;
    }
    __syncthreads();
    int cnt_gt = (int)s_red[0][0] + (int)s_red[0][1] +
                 (int)s_red[0][2] + (int)s_red[0][3];
    int keep_eq = KK - cnt_gt;         // #ties kept, ascending index (stable top_k)

    // --- exclusive prefix of equality counts across threads (ascending n) ---
    int lsum = 0;
    #pragma unroll
    for (int k = 0; k < 16; ++k) lsum += (int)(u[k] == T);
    int incl = lsum;
    #pragma unroll
    for (int off = 1; off < 64; off <<= 1) {
        int v = __shfl_up(incl, off, 64);
        if (lane >= off) incl += v;
    }
    if (lane == 63) s_scan[wave] = (unsigned)incl;
    __syncthreads();
    int woff = 0;
    for (int w = 0; w < wave; ++w) woff += (int)s_scan[w];
    int run = woff + incl - lsum;      // equal-count before this thread's chunk

    // --- emit mask ---
    #pragma unroll
    for (int k = 0; k < 4; ++k) {
        float4 m;
        float* mp = (float*)&m;
        #pragma unroll
        for (int j = 0; j < 4; ++j) {
            unsigned uv = u[4 * k + j];
            int e = (uv == T);
            mp[j] = ((uv > T) || (e && run < keep_eq)) ? 1.f : 0.f;
            run += e;
        }
        ((float4*)(mask + (size_t)b * NN))[tid * 4 + k] = m;
    }
}

// ---------------- R8 fused resident kernel ----------------
// sync[0]            : barrier-A counter (memset to 0 pre-launch)
// sync[16 + b*32]    : per-batch mask-ready flag, set to MAGIC (release)
__global__ __launch_bounds__(256) void k_fused(const float* __restrict__ x,
                                               float* __restrict__ out,
                                               float* __restrict__ sq,
                                               float* __restrict__ mask,
                                               unsigned* sync) {
    const int blk = blockIdx.x;        // 0..511
    const int tid = threadIdx.x;       // 0..255

    // ===== Phase 1: sq[b,t,n] = sqrt(sum_c x^2)  (exact k_sq body) =====
    {
        int idx = blk * 256 + tid;                     // exactly NB*NT*(NN/4)
        int n4 = (idx & (NN / 4 - 1));
        int bt = idx >> 10;
        const float4* xp = (const float4*)(x + (size_t)bt * NC * NN) + n4;
        float a0 = 0.f, a1 = 0.f, a2 = 0.f, a3 = 0.f;
        #pragma unroll 16
        for (int c = 0; c < NC; ++c) {
            float4 v = xp[c * (NN / 4)];
            a0 = __fadd_rn(a0, __fmul_rn(v.x, v.x));
            a1 = __fadd_rn(a1, __fmul_rn(v.y, v.y));
            a2 = __fadd_rn(a2, __fmul_rn(v.z, v.z));
            a3 = __fadd_rn(a3, __fmul_rn(v.w, v.w));
        }
        float4 r;
        r.x = __fsqrt_rn(a0);
        r.y = __fsqrt_rn(a1);
        r.z = __fsqrt_rn(a2);
        r.w = __fsqrt_rn(a3);
        ((float4*)sq)[idx] = r;
    }

    // ===== Barrier A: all 512 blocks (all co-resident at 2 blocks/CU) =====
    __syncthreads();                                   // drains vmem (compiler waitcnt)
    if (tid == 0) {
        __threadfence();                               // release sq stores
        atomicAdd(&sync[0], 1u);                       // device-scope
    }
    while (__hip_atomic_load(&sync[0], __ATOMIC_ACQUIRE,
                             __HIP_MEMORY_SCOPE_AGENT) < 512u)
        __builtin_amdgcn_s_sleep(8);

    // ===== Phase 2: select, blocks 0..7 (exact k_select_fused body) =====
    if (blk < NB) {
        const int b = blk;
        float acc[16];
        #pragma unroll
        for (int k = 0; k < 16; ++k) acc[k] = 0.f;
        const float* sb = sq + (size_t)b * NT * NN + tid * 16;
        #pragma unroll
        for (int t = 0; t < NT; ++t) {
            const float4* sp = (const float4*)(sb + (size_t)t * NN);
            #pragma unroll
            for (int k = 0; k < 4; ++k) {
                float4 v = sp[k];
                acc[4 * k + 0] = __fadd_rn(acc[4 * k + 0], v.x);
                acc[4 * k + 1] = __fadd_rn(acc[4 * k + 1], v.y);
                acc[4 * k + 2] = __fadd_rn(acc[4 * k + 2], v.z);
                acc[4 * k + 3] = __fadd_rn(acc[4 * k + 3], v.w);
            }
        }
        unsigned u[16];
        #pragma unroll
        for (int k = 0; k < 16; ++k)
            u[k] = __float_as_uint(__fmul_rn(acc[k], 0.0625f));

        topk_emit_mask(u, b, tid, mask);

        __syncthreads();                               // all mask stores issued
        if (tid == 0) {
            __threadfence();                           // release mask stores
            __hip_atomic_store(&sync[16 + b * 32], MAGIC, __ATOMIC_RELEASE,
                               __HIP_MEMORY_SCOPE_AGENT);
        }
    }

    // ===== Phase 3: apply; wait only on own batch's flag =====
    const int b3 = blk >> 6;                           // 64 blocks per batch
    const int r3 = blk & 63;
    while (__hip_atomic_load(&sync[16 + b3 * 32], __ATOMIC_ACQUIRE,
                             __HIP_MEMORY_SCOPE_AGENT) != MAGIC)
        __builtin_amdgcn_s_sleep(32);

    const float4* mb = (const float4*)mask + b3 * (NN / 4);
    size_t i = (size_t)b3 * (NT * NC * NN / 4) + (size_t)r3 * 16384 + tid;
    #pragma unroll 4
    for (int it = 0; it < 64; ++it, i += 256) {
        int n4 = (int)(i & (NN / 4 - 1));
        float4 v = ((const float4*)x)[i];
        float4 m = mb[n4];
        vf4 r;
        r.x = (m.x != 0.f) ? v.x : 0.f;
        r.y = (m.y != 0.f) ? v.y : 0.f;
        r.z = (m.z != 0.f) ? v.z : 0.f;
        r.w = (m.w != 0.f) ? v.w : 0.f;
        __builtin_nontemporal_store(r, (vf4*)out + i);
    }
}

// ================= Fallback path (ws too small for fused layout) ==============
__global__ __launch_bounds__(256) void k_score_fused(const float* __restrict__ x,
                                                     float* __restrict__ scores) {
    int idx = blockIdx.x * 256 + threadIdx.x;
    if (idx >= NB * NN) return;
    int b = idx >> 12;
    int n = idx & (NN - 1);
    const float* xb = x + (size_t)b * NT * NC * NN + n;
    float at = 0.f;
    for (int t = 0; t < NT; ++t) {
        float ac = 0.f;
        #pragma unroll 8
        for (int c = 0; c < NC; ++c) {
            float v = xb[(size_t)(t * NC + c) * NN];
            ac = __fadd_rn(ac, __fmul_rn(v, v));
        }
        at = __fadd_rn(at, __fsqrt_rn(ac));
    }
    scores[idx] = __fmul_rn(at, 0.0625f);
}

__global__ __launch_bounds__(256) void k_select3(const float* __restrict__ scores,
                                                 float* __restrict__ mask) {
    int b = blockIdx.x;
    int tid = threadIdx.x;
    unsigned u[16];
    const float4* sp = (const float4*)(scores + (size_t)b * NN);
    #pragma unroll
    for (int k = 0; k < 4; ++k) {
        float4 v = sp[tid * 4 + k];
        u[4 * k + 0] = __float_as_uint(v.x);
        u[4 * k + 1] = __float_as_uint(v.y);
        u[4 * k + 2] = __float_as_uint(v.z);
        u[4 * k + 3] = __float_as_uint(v.w);
    }
    topk_emit_mask(u, b, tid, mask);
}

__global__ __launch_bounds__(256) void k_apply(const float* __restrict__ x,
                                               const float* __restrict__ mask,
                                               float* __restrict__ out) {
    size_t i = (size_t)blockIdx.x * 256 + threadIdx.x; // over total/4
    int b = (int)(i >> 20);                            // NT*NC*NN/4 = 2^20 per batch
    int n4 = (int)(i & (NN / 4 - 1));
    vf4 v = __builtin_nontemporal_load((const vf4*)x + i);
    float4 m = ((const float4*)mask)[b * (NN / 4) + n4];
    vf4 r;
    r.x = (m.x != 0.f) ? v.x : 0.f;
    r.y = (m.y != 0.f) ? v.y : 0.f;
    r.z = (m.z != 0.f) ? v.z : 0.f;
    r.w = (m.w != 0.f) ? v.w : 0.f;
    __builtin_nontemporal_store(r, (vf4*)out + i);
}

extern "C" void kernel_launch(void* const* d_in, const int* in_sizes, int n_in,
                              void* d_out, int out_size, void* d_ws, size_t ws_size,
                              hipStream_t stream) {
    const float* x = (const float*)d_in[0];
    float* out = (float*)d_out;
    float* ws = (float*)d_ws;

    // ws layout (floats): mask [NB*NN] | scores [NB*NN] | sq [NB*NT*NN] | sync [1024 u32]
    float* mask   = ws;
    float* scores = ws + NB * NN;
    float* sq     = ws + 2 * NB * NN;
    unsigned* sync = (unsigned*)(ws + 2 * NB * NN + NB * NT * NN);
    const size_t need_fused = (size_t)(2 * NB * NN + NB * NT * NN) * sizeof(float)
                              + 1024 * sizeof(unsigned);
    const size_t need_slow = (size_t)(2 * NB * NN) * sizeof(float);

    if (ws_size >= need_fused) {
        hipMemsetAsync(sync, 0, 4096, stream);         // zero barrier counter + flags
        k_fused<<<512, 256, 0, stream>>>(x, out, sq, mask, sync);
    } else if (ws_size >= need_slow) {
        k_score_fused<<<(NB * NN + 255) / 256, 256, 0, stream>>>(x, scores);
        k_select3<<<NB, 256, 0, stream>>>(scores, mask);
        k_apply<<<NB * NT * NC * (NN / 4) / 256, 256, 0, stream>>>(x, mask, out);
    }
}

// Round 6
// 257.683 us; speedup vs baseline: 1.9297x; 1.9297x over previous
//
#include <hip/hip_runtime.h>

// Problem: x [B=8, T=16, C=64, H=64, W=64] fp32.
// out = x masked by per-batch top-K (K=2048 of N=4096) spatial sites,
// score[b,n] = mean_t sqrt(sum_c x[b,t,c,n]^2).
//
// Scores computed BIT-IDENTICALLY to numpy (sequential ascending-index
// accumulation, unfused mul/add, IEEE sqrt, *0.0625) -> kept set matches the
// reference exactly -> absmax 0 (verified R1-R8).
//
// R9: REVERT to the session-best R4 structure (257.66us, absmax 0).
// Post-R8 evidence: (1) R8's fused-kernel counters prove the pipeline's HBM
// traffic is already structurally minimal (272MB total; x re-read fully
// L3-absorbed); (2) resident spin-sync costs 246us extra (agent-scope acquire
// polling serializes the non-coherent-L2 coherence point; VALUBusy 0.8%);
// (3) launch-boundary removal is worth ~0 (R6); (4) cache-policy changes are
// neutral (R7). Remaining dur_us is dominated by harness-fixed work
// (2x512MiB poison fills = ~157us, counter-verified). This revert restores
// the best measured artifact.

constexpr int NB = 8;
constexpr int NT = 16;
constexpr int NC = 64;
constexpr int NN = 4096;   // H*W
constexpr int KK = 2048;   // keep_k

typedef float vf4 __attribute__((ext_vector_type(4)));  // raw vec for nt builtins

// ---------------- Kernel A: sq[b,t,n] = sqrt(sum_c x[b,t,c,n]^2) ----------------
__global__ __launch_bounds__(256) void k_sq(const float* __restrict__ x,
                                            float* __restrict__ sq) {
    int idx = blockIdx.x * 256 + threadIdx.x;          // over NB*NT*(NN/4)
    if (idx >= NB * NT * (NN / 4)) return;
    int n4 = (idx & (NN / 4 - 1));
    int bt = idx >> 10;
    const float4* xp = (const float4*)(x + (size_t)bt * NC * NN) + n4;
    float a0 = 0.f, a1 = 0.f, a2 = 0.f, a3 = 0.f;
    #pragma unroll 16
    for (int c = 0; c < NC; ++c) {
        float4 v = xp[c * (NN / 4)];
        a0 = __fadd_rn(a0, __fmul_rn(v.x, v.x));
        a1 = __fadd_rn(a1, __fmul_rn(v.y, v.y));
        a2 = __fadd_rn(a2, __fmul_rn(v.z, v.z));
        a3 = __fadd_rn(a3, __fmul_rn(v.w, v.w));
    }
    float4 r;
    r.x = __fsqrt_rn(a0);
    r.y = __fsqrt_rn(a1);
    r.z = __fsqrt_rn(a2);
    r.w = __fsqrt_rn(a3);
    ((float4*)sq)[idx] = r;
}

// ---------------- Kernel B: score[b,n] = (sum_t sq[b,t,n]) * (1/16) ----------------
__global__ __launch_bounds__(256) void k_score(const float* __restrict__ sq,
                                               float* __restrict__ scores) {
    int idx = blockIdx.x * 256 + threadIdx.x;          // over NB*(NN/4) -> 32 blocks
    if (idx >= NB * (NN / 4)) return;
    int b = idx >> 10;
    int n4 = idx & (NN / 4 - 1);
    const float4* sp = (const float4*)(sq + (size_t)b * NT * NN) + n4;
    float a0 = 0.f, a1 = 0.f, a2 = 0.f, a3 = 0.f;
    #pragma unroll
    for (int t = 0; t < NT; ++t) {
        float4 v = sp[t * (NN / 4)];
        a0 = __fadd_rn(a0, v.x);
        a1 = __fadd_rn(a1, v.y);
        a2 = __fadd_rn(a2, v.z);
        a3 = __fadd_rn(a3, v.w);
    }
    float4 r;
    r.x = __fmul_rn(a0, 0.0625f);
    r.y = __fmul_rn(a1, 0.0625f);
    r.z = __fmul_rn(a2, 0.0625f);
    r.w = __fmul_rn(a3, 0.0625f);
    ((float4*)scores)[idx] = r;
}

// ---------------- Fallback score (ws too small for sq) ----------------
__global__ __launch_bounds__(256) void k_score_fused(const float* __restrict__ x,
                                                     float* __restrict__ scores) {
    int idx = blockIdx.x * 256 + threadIdx.x;
    if (idx >= NB * NN) return;
    int b = idx >> 12;
    int n = idx & (NN - 1);
    const float* xb = x + (size_t)b * NT * NC * NN + n;
    float at = 0.f;
    for (int t = 0; t < NT; ++t) {
        float ac = 0.f;
        #pragma unroll 8
        for (int c = 0; c < NC; ++c) {
            float v = xb[(size_t)(t * NC + c) * NN];
            ac = __fadd_rn(ac, __fmul_rn(v, v));
        }
        at = __fadd_rn(at, __fsqrt_rn(ac));
    }
    scores[idx] = __fmul_rn(at, 0.0625f);
}

// ---------------- Kernel C: top-K mask, bit-bisection w/ prefix skip ----------------
// One block (256 threads = 4 waves) per batch; thread owns 16 consecutive sites.
__global__ __launch_bounds__(256) void k_select3(const float* __restrict__ scores,
                                                 float* __restrict__ mask) {
    __shared__ unsigned s_red[2][4];
    __shared__ unsigned s_scan[4];

    int b = blockIdx.x;
    int tid = threadIdx.x;
    int wave = tid >> 6, lane = tid & 63;

    // load 16 scores (sites tid*16 .. tid*16+15); nonneg -> bits order-preserving
    unsigned u[16];
    const float4* sp = (const float4*)(scores + (size_t)b * NN);
    #pragma unroll
    for (int k = 0; k < 4; ++k) {
        float4 v = sp[tid * 4 + k];
        u[4 * k + 0] = __float_as_uint(v.x);
        u[4 * k + 1] = __float_as_uint(v.y);
        u[4 * k + 2] = __float_as_uint(v.z);
        u[4 * k + 3] = __float_as_uint(v.w);
    }

    // --- block min/max of u -> common high-bit prefix ---
    unsigned lmin = u[0], lmax = u[0];
    #pragma unroll
    for (int k = 1; k < 16; ++k) {
        lmin = min(lmin, u[k]);
        lmax = max(lmax, u[k]);
    }
    #pragma unroll
    for (int off = 32; off > 0; off >>= 1) {
        lmin = min(lmin, (unsigned)__shfl_down((int)lmin, off, 64));
        lmax = max(lmax, (unsigned)__shfl_down((int)lmax, off, 64));
    }
    if (lane == 0) { s_red[0][wave] = lmin; s_red[1][wave] = lmax; }
    __syncthreads();
    unsigned umin = s_red[0][0], umax = s_red[1][0];
    #pragma unroll
    for (int w = 1; w < 4; ++w) {
        umin = min(umin, s_red[0][w]);
        umax = max(umax, s_red[1][w]);
    }
    __syncthreads();

    // --- bisection: max T with count(u >= T) >= KK (T = K-th largest bits) ---
    unsigned T;
    if (umax == umin) {
        T = umax;                      // all equal: pure tie case
    } else {
        int hb = 31 - __clz(umax ^ umin);      // hb <= 30 (scores >= 0)
        T = umax & ~((2u << hb) - 1);          // shared prefix, low bits 0
        for (int bit = hb; bit >= 0; --bit) {
            unsigned C = T | (1u << bit);
            int local = 0;
            #pragma unroll
            for (int k = 0; k < 16; ++k) local += (int)(u[k] >= C);
            #pragma unroll
            for (int off = 32; off > 0; off >>= 1)
                local += __shfl_down(local, off, 64);
            if (lane == 0) s_red[bit & 1][wave] = (unsigned)local;
            __syncthreads();
            int total = (int)s_red[bit & 1][0] + (int)s_red[bit & 1][1] +
                        (int)s_red[bit & 1][2] + (int)s_red[bit & 1][3];
            if (total >= KK) T = C;
            // alternating slot: entry reused two iters later, separated by a sync
        }
    }

    // --- cnt_gt = count(u > T) ---
    {
        int local = 0;
        #pragma unroll
        for (int k = 0; k < 16; ++k) local += (int)(u[k] > T);
        #pragma unroll
        for (int off = 32; off > 0; off >>= 1)
            local += __shfl_down(local, off, 64);
        __syncthreads();
        if (lane == 0) s_red[0][wave] = (unsigned)local;
    }
    __syncthreads();
    int cnt_gt = (int)s_red[0][0] + (int)s_red[0][1] +
                 (int)s_red[0][2] + (int)s_red[0][3];
    int keep_eq = KK - cnt_gt;         // #ties kept, ascending index (stable top_k)

    // --- exclusive prefix of equality counts across threads (ascending n) ---
    int lsum = 0;
    #pragma unroll
    for (int k = 0; k < 16; ++k) lsum += (int)(u[k] == T);
    int incl = lsum;
    #pragma unroll
    for (int off = 1; off < 64; off <<= 1) {
        int v = __shfl_up(incl, off, 64);
        if (lane >= off) incl += v;
    }
    if (lane == 63) s_scan[wave] = (unsigned)incl;
    __syncthreads();
    int woff = 0;
    for (int w = 0; w < wave; ++w) woff += (int)s_scan[w];
    int run = woff + incl - lsum;      // equal-count before this thread's chunk

    // --- emit mask ---
    #pragma unroll
    for (int k = 0; k < 4; ++k) {
        float4 m;
        float* mp = (float*)&m;
        #pragma unroll
        for (int j = 0; j < 4; ++j) {
            unsigned uv = u[4 * k + j];
            int e = (uv == T);
            mp[j] = ((uv > T) || (e && run < keep_eq)) ? 1.f : 0.f;
            run += e;
        }
        ((float4*)(mask + (size_t)b * NN))[tid * 4 + k] = m;
    }
}

// ---------------- Kernel D: out = mask ? x : 0 ----------------
__global__ __launch_bounds__(256) void k_apply(const float* __restrict__ x,
                                               const float* __restrict__ mask,
                                               float* __restrict__ out) {
    size_t i = (size_t)blockIdx.x * 256 + threadIdx.x; // over total/4
    int b = (int)(i >> 20);                            // NT*NC*NN/4 = 2^20 per batch
    int n4 = (int)(i & (NN / 4 - 1));
    vf4 v = __builtin_nontemporal_load((const vf4*)x + i);
    float4 m = ((const float4*)mask)[b * (NN / 4) + n4];
    vf4 r;
    r.x = (m.x != 0.f) ? v.x : 0.f;
    r.y = (m.y != 0.f) ? v.y : 0.f;
    r.z = (m.z != 0.f) ? v.z : 0.f;
    r.w = (m.w != 0.f) ? v.w : 0.f;
    __builtin_nontemporal_store(r, (vf4*)out + i);
}

extern "C" void kernel_launch(void* const* d_in, const int* in_sizes, int n_in,
                              void* d_out, int out_size, void* d_ws, size_t ws_size,
                              hipStream_t stream) {
    const float* x = (const float*)d_in[0];
    float* out = (float*)d_out;
    float* ws = (float*)d_ws;

    // ws layout (floats): mask [NB*NN] | scores [NB*NN] | sq [NB*NT*NN]
    float* mask   = ws;
    float* scores = ws + NB * NN;
    float* sq     = ws + 2 * NB * NN;
    const size_t need_fast = (size_t)(2 * NB * NN + NB * NT * NN) * sizeof(float);

    if (ws_size >= need_fast) {
        k_sq<<<(NB * NT * (NN / 4) + 255) / 256, 256, 0, stream>>>(x, sq);
        k_score<<<(NB * (NN / 4) + 255) / 256, 256, 0, stream>>>(sq, scores);
    } else {
        k_score_fused<<<(NB * NN + 255) / 256, 256, 0, stream>>>(x, scores);
    }
    k_select3<<<NB, 256, 0, stream>>>(scores, mask);
    k_apply<<<(NB * NT * NC * (NN / 4)) / 256, 256, 0, stream>>>(x, mask, out);
}